// Round 14
// baseline (56.194 us; speedup 1.0000x reference)
//
#include <hip/hip_runtime.h>

typedef __attribute__((ext_vector_type(8))) short bfrag;   // 8 bf16 = 4 VGPR
typedef __attribute__((ext_vector_type(4))) float f32x4;

namespace {
constexpr int N_ = 16, C_ = 112, H_ = 48, W_ = 48, HW_ = 2304;
constexpr int NKS = 18;  // K-slices of 128 (18*128 = 2304)
// ws float offsets
constexpr int WS_T7 = 0;          // 768
constexpr int WS_A = 1024;        // 1792 -> 2816
constexpr int WS_WPACK = 40960;   // 3*112*128 bf16 = 21504 f -> 62464
constexpr int WS_GBF = 62464;     // 16*112*128 bf16 = 114688 f -> 177152
constexpr int WS_SPART = 177152;  // 18*16*112*128 f32 = 4128768 -> 4305920 (17.2 MB)
}

__device__ __forceinline__ float f4e(const float4& v, int e) {
  return e == 0 ? v.x : e == 1 ? v.y : e == 2 ? v.z : v.w;
}
__device__ __forceinline__ unsigned short f2bf(float f) {  // RNE
  unsigned u = __float_as_uint(f);
  return (unsigned short)((u + 0x7FFFu + ((u >> 16) & 1u)) >> 16);
}
__device__ __forceinline__ float bf2f(unsigned short s) {
  return __uint_as_float(((unsigned)s) << 16);
}

// ---------------------------------------------------------------------------
// K1: t7 as a 48-tap projection of x rows, coalesced: 12 consecutive lanes
// read one contiguous 192B row. t7[n,h'] = (1/112) sum_c dot(x[n,c,h',:], q),
// q[j] = sum_k p7[k][j+3-3k]; value lands at (h'+2)%48 (S3=+1,S6=+1 -> +2).
// grid (48, 16), 192 threads.
__global__ __launch_bounds__(192) void ath_t7(const float* __restrict__ x,
                                              const float* __restrict__ p7,
                                              float* __restrict__ ws) {
  const int h = blockIdx.x, n = blockIdx.y;
  const int tid = threadIdx.x;
  __shared__ float q[48];
  __shared__ float wred[3];
  if (tid < 48) {
    float s = 0.f;
#pragma unroll
    for (int k = 0; k < 3; ++k) {
      int wp = tid + 3 - 3 * k;
      if (wp >= 0 && wp < 48) s += p7[k * 48 + wp];
    }
    q[tid] = s;
  }
  __syncthreads();
  const int c16 = tid / 12, qq = tid - 12 * c16;
  const float qv0 = q[4 * qq], qv1 = q[4 * qq + 1];
  const float qv2 = q[4 * qq + 2], qv3 = q[4 * qq + 3];
  float d = 0.f;
#pragma unroll
  for (int p = 0; p < 7; ++p) {
    const int c = c16 + 16 * p;
    float4 v = *(const float4*)&x[((size_t)n * C_ + c) * HW_ + h * W_ + 4 * qq];
    d += v.x * qv0 + v.y * qv1 + v.z * qv2 + v.w * qv3;
  }
#pragma unroll
  for (int off = 32; off >= 1; off >>= 1) d += __shfl_xor(d, off);
  if ((tid & 63) == 0) wred[tid >> 6] = d;
  __syncthreads();
  if (tid == 0)
    ws[WS_T7 + n * H_ + (h + 2) % 48] =
        (wred[0] + wred[1] + wred[2]) * (1.0f / 112.0f);
}

// ---------------------------------------------------------------------------
// K2: Gram via MFMA, st17-augmented A (LDS) x raw-x B (register-prefetched),
// virtual t7 B-row for A'. Block = (n, ks, half): half owns ti = wv + 4*half.
// t17 recomputed per block from t7 (cheap). Tail blocks: wpack.
// grid 576 + 42, 256 threads.
__global__ __launch_bounds__(256) void ath_gram(const float* __restrict__ x,
                                                const float* __restrict__ cw,
                                                float* __restrict__ ws) {
  const int bid = blockIdx.x;
  const int tid = threadIdx.x;
  if (bid >= 2 * NKS * N_) {  // ---- wpack tail: bf16 [kx][o][i pad 128]
    int idx = (bid - 2 * NKS * N_) * 256 + tid;
    if (idx < 3 * 112 * 32) {
      int kx = idx / (112 * 32);
      int r = idx - kx * 112 * 32;
      int o = r >> 5;
      int i0 = (r & 31) * 4;
      unsigned short v[4];
#pragma unroll
      for (int e = 0; e < 4; ++e) {
        int i = i0 + e;
        v[e] = (i < 112) ? f2bf(cw[o * 336 + i * 3 + kx]) : (unsigned short)0;
      }
      unsigned short* wp = (unsigned short*)(ws + WS_WPACK);
      *(ushort4*)&wp[(kx * 112 + o) * 128 + i0] = make_ushort4(v[0], v[1], v[2], v[3]);
    }
    return;
  }
  const int half = bid & 1;
  const int ks = (bid >> 1) % NKS;
  const int n = bid / (2 * NKS);
  const int k0 = ks * 128;
  const int lane = tid & 63, wv = tid >> 6;
  const int lr = lane & 15, lg = lane >> 4;
  __shared__ __align__(16) unsigned short As[112][136];
  __shared__ __align__(16) unsigned short t7r[136];
  __shared__ float t7s[48];
  __shared__ float s17[8];
  if (tid < 48) t7s[tid] = ws[WS_T7 + n * H_ + tid];
  __syncthreads();
  if (tid < 7) {  // t17[kk] = (1/48) sum_h |t7pad[2kk+h-6]|
    float s = 0.f;
    for (int hh = 0; hh < 48; ++hh) {
      int j = 2 * tid + hh - 6;
      if (j >= 0 && j < 48) s += fabsf(t7s[j]);
    }
    s17[tid] = s * (1.0f / 48.0f);
  }
  if (tid >= 64 && tid < 192) t7r[tid - 64] = f2bf(t7s[(k0 + tid - 64) / 48]);
  if (tid >= 192 && tid < 200) t7r[128 + (tid - 192)] = 0;
  // prefetch B fragments into registers (no LDS dependency; overlaps)
  const int ti = wv + 4 * half;  // this wave's output column-group (0..7)
  bfrag breg[4];
  if (ti < 7) {
    const float* bp = &x[((size_t)n * C_ + 16 * ti + lr) * HW_ + k0 + 8 * lg];
#pragma unroll
    for (int kb = 0; kb < 4; ++kb) {
      float4 v0 = *(const float4*)(bp + 32 * kb);
      float4 v1 = *(const float4*)(bp + 32 * kb + 4);
      breg[kb][0] = (short)f2bf(v0.x); breg[kb][1] = (short)f2bf(v0.y);
      breg[kb][2] = (short)f2bf(v0.z); breg[kb][3] = (short)f2bf(v0.w);
      breg[kb][4] = (short)f2bf(v1.x); breg[kb][5] = (short)f2bf(v1.y);
      breg[kb][6] = (short)f2bf(v1.z); breg[kb][7] = (short)f2bf(v1.w);
    }
  }
  __syncthreads();  // s17/t7r visible to ALL waves before A staging reads s17
  // stage augmented A: As[c][p-k0] = bf16(x[c,p] + s17[(c+p)%7])
  const int kq = tid & 31, cg = tid >> 5;
  const int base7 = (k0 + 4 * kq) % 7;
#pragma unroll
  for (int r = 0; r < 14; ++r) {
    const int c = cg + 8 * r;
    float4 v = *(const float4*)&x[((size_t)n * C_ + c) * HW_ + k0 + 4 * kq];
    int cls0 = (base7 + c) % 7;
    unsigned short a4[4];
#pragma unroll
    for (int e = 0; e < 4; ++e) {
      int cl = cls0 + e;
      cl = (cl >= 7) ? cl - 7 : cl;
      a4[e] = f2bf(f4e(v, e) + s17[cl]);
    }
    *(ushort4*)&As[c][4 * kq] = make_ushort4(a4[0], a4[1], a4[2], a4[3]);
  }
  __syncthreads();
  if (ti == 7) {
    const bfrag zero8 = {0, 0, 0, 0, 0, 0, 0, 0};
#pragma unroll
    for (int kb = 0; kb < 4; ++kb)
      breg[kb] = (lr == 0) ? *(const bfrag*)&t7r[8 * lg + 32 * kb] : zero8;
  }
  f32x4 acc[7];
#pragma unroll
  for (int j = 0; j < 7; ++j) acc[j] = (f32x4){0.f, 0.f, 0.f, 0.f};
#pragma unroll
  for (int kb = 0; kb < 4; ++kb) {
#pragma unroll
    for (int tc = 0; tc < 7; ++tc) {
      bfrag a = *(const bfrag*)&As[16 * tc + lr][8 * lg + 32 * kb];
      acc[tc] = __builtin_amdgcn_mfma_f32_16x16x32_bf16(a, breg[kb], acc[tc], 0, 0, 0);
    }
  }
  float* sp = ws + WS_SPART + (size_t)(n * NKS + ks) * 14336;
#pragma unroll
  for (int tc = 0; tc < 7; ++tc)
#pragma unroll
    for (int e = 0; e < 4; ++e)
      sp[(16 * tc + 4 * lg + e) * 128 + 16 * ti + lr] = acc[tc][e];
}

// ---------------------------------------------------------------------------
// K3: reduce SPART -> Gbf (bf16, cols>=112 zero) + A'. grid N*28, 128 thr.
__global__ __launch_bounds__(128) void ath_assemble(const float* __restrict__ p19,
                                                    float* __restrict__ ws) {
  const int bid = blockIdx.x;
  const int n = bid / 28, g = bid % 28;
  const int tid = threadIdx.x;
  const int cloc = tid >> 5, q = tid & 31;
  const int c = 4 * g + cloc;
  const int i0 = 4 * q;
  float4 s = make_float4(0.f, 0.f, 0.f, 0.f);
#pragma unroll
  for (int ks = 0; ks < NKS; ++ks) {
    float4 t = *(const float4*)&ws[WS_SPART + (size_t)(n * NKS + ks) * 14336 + c * 128 + i0];
    s.x += t.x; s.y += t.y; s.z += t.z; s.w += t.w;
  }
  unsigned short* gb = (unsigned short*)(ws + WS_GBF);
  if (i0 < 112) {
    const float scale = 1.0f / (48.0f * sqrtf(112.0f));
    const float pc = p19[c];
    *(ushort4*)&gb[((size_t)n * C_ + c) * 128 + i0] =
        make_ushort4(f2bf(pc * s.x * scale), f2bf(pc * s.y * scale),
                     f2bf(pc * s.z * scale), f2bf(pc * s.w * scale));
  } else {
    *(ushort4*)&gb[((size_t)n * C_ + c) * 128 + i0] = make_ushort4(0, 0, 0, 0);
    if (i0 == 112) ws[WS_A + n * C_ + c] = p19[c] * s.x * (2.0f / 48.0f);
  }
}

// ---------------------------------------------------------------------------
// K4 fused via MFMA, LDS-stationary operands + T14 async re-stage: next buf
// slice's loads are issued into registers at the TOP of each kx MFMA phase
// (latency hides under MFMA), ds_write after the barrier. xT[52][136] bf16
// transposed x-slab; buf[112][136] = wp slice kx, then Gbf. t13 in-place.
// 21 16x16 tiles round-robin over 4 waves. LDS ~45 KB (3 blocks/CU).
__global__ __launch_bounds__(256) void ath_fused(const float* __restrict__ x,
                                                 const float* __restrict__ ws,
                                                 float* __restrict__ out) {
  const int h = blockIdx.x, n = blockIdx.y;
  const int tid = threadIdx.x;
  const int lane = tid & 63, wv = tid >> 6;
  const int lr = lane & 15, lg = lane >> 4;
  __shared__ __align__(16) unsigned short xT[52][136];
  __shared__ __align__(16) unsigned short buf[112][136];
  __shared__ float sA[112];
  const float* xb = x + (size_t)n * C_ * HW_ + h * W_;
  const unsigned short* wp = (const unsigned short*)(ws + WS_WPACK);
  const unsigned short* gb = (const unsigned short*)(ws + WS_GBF) + (size_t)n * C_ * 128;
  // zero pads
  for (int idx = tid; idx < 52 * 24; idx += 256) {
    int r2 = idx / 24, cc = 112 + idx % 24;
    xT[r2][cc] = 0;
  }
  for (int idx = tid; idx < 4 * 112; idx += 256) {
    int rr = idx / 112;
    int r2 = (rr < 2) ? rr : 48 + rr;
    xT[r2][idx % 112] = 0;
  }
  if (tid < 112) sA[tid] = ws[WS_A + n * C_ + tid];
  // stage x -> xT bf16 (transpose, packed 2-channel u32 writes)
  for (int idx = tid; idx < 672; idx += 256) {
    int i2 = idx / 12, q = idx - i2 * 12;
    float4 a = *(const float4*)&xb[(size_t)(2 * i2) * HW_ + 4 * q];
    float4 b = *(const float4*)&xb[(size_t)(2 * i2 + 1) * HW_ + 4 * q];
#pragma unroll
    for (int e = 0; e < 4; ++e) {
      unsigned pk = (unsigned)f2bf(f4e(a, e)) | ((unsigned)f2bf(f4e(b, e)) << 16);
      *(unsigned*)&xT[4 * q + 2 + e][2 * i2] = pk;
    }
  }
  // stage wp slice 0 into buf (cold, nothing to overlap)
  for (int idx = tid; idx < 1792; idx += 256) {
    int row = idx >> 4, cq = idx & 15;
    *(float4*)&buf[row][cq * 8] = *(const float4*)&wp[(size_t)row * 128 + cq * 8];
  }
  __syncthreads();

  // ---- conv phase, kx-outer, accs persistent; T14 prefetch of next slice
  f32x4 acc[6];
#pragma unroll
  for (int j = 0; j < 6; ++j) acc[j] = (f32x4){0.f, 0.f, 0.f, 0.f};
  unsigned short tv[6][4];
#pragma unroll
  for (int kx = 0; kx < 3; ++kx) {
    // issue next-buffer loads into regs (wp slice kx+1, or Gbf for kx==2)
    const unsigned short* nsrc = (kx < 2) ? wp + (size_t)(kx + 1) * 112 * 128 : gb;
    float4 pf[7];
#pragma unroll
    for (int it = 0; it < 7; ++it) {
      int idx = tid + 256 * it;  // 7*256 == 1792 exactly
      int row = idx >> 4, cq = idx & 15;
      pf[it] = *(const float4*)&nsrc[(size_t)row * 128 + cq * 8];
    }
    __builtin_amdgcn_sched_barrier(0);  // pin load issue above MFMA phase
#pragma unroll
    for (int j = 0; j < 6; ++j) {
      int t = wv + 4 * j;
      if (t < 21) {
        int m = t / 3, nt = t - 3 * m;
        int o0 = m * 16, w0 = nt * 16;
#pragma unroll
        for (int kb = 0; kb < 4; ++kb) {
          bfrag a = *(const bfrag*)&buf[o0 + lr][8 * lg + 32 * kb];
          bfrag b = *(const bfrag*)&xT[w0 + lr + 2 * kx][8 * lg + 32 * kb];
          acc[j] = __builtin_amdgcn_mfma_f32_16x16x32_bf16(a, b, acc[j], 0, 0, 0);
        }
      }
    }
    if (kx == 2) {  // t13 = max(-conv, x) (reads xT before it's overwritten)
#pragma unroll
      for (int j = 0; j < 6; ++j) {
        int t = wv + 4 * j;
        if (t < 21) {
          int m = t / 3, nt = t - 3 * m;
          int o0 = m * 16, w0 = nt * 16;
#pragma unroll
          for (int e = 0; e < 4; ++e) {
            float xv = bf2f(xT[w0 + lr + 2][o0 + 4 * lg + e]);
            tv[j][e] = f2bf(fmaxf(-acc[j][e], xv));
          }
        }
      }
    }
    __syncthreads();  // all reads of buf (and xT for kx==2) complete
    if (kx == 2) {    // write t13 into xT
#pragma unroll
      for (int j = 0; j < 6; ++j) {
        int t = wv + 4 * j;
        if (t < 21) {
          int m = t / 3, nt = t - 3 * m;
          int o0 = m * 16, w0 = nt * 16;
          unsigned pk0 = (unsigned)tv[j][0] | ((unsigned)tv[j][1] << 16);
          unsigned pk1 = (unsigned)tv[j][2] | ((unsigned)tv[j][3] << 16);
          *(unsigned*)&xT[w0 + lr + 2][o0 + 4 * lg] = pk0;
          *(unsigned*)&xT[w0 + lr + 2][o0 + 4 * lg + 2] = pk1;
        }
      }
    }
#pragma unroll
    for (int it = 0; it < 7; ++it) {
      int idx = tid + 256 * it;
      int row = idx >> 4, cq = idx & 15;
      *(float4*)&buf[row][cq * 8] = pf[it];
    }
    __syncthreads();  // new buf (+ t13 for kx==2) visible
  }

  // ---- final GEMM: out[c][w] = A'[c] - sum_i G'[c][i] * t13[i][w]
#pragma unroll
  for (int j = 0; j < 6; ++j) {
    int t = wv + 4 * j;
    if (t < 21) {
      int m = t / 3, nt = t - 3 * m;
      int c0 = m * 16, w0 = nt * 16;
      f32x4 acc2 = {0.f, 0.f, 0.f, 0.f};
#pragma unroll
      for (int kb = 0; kb < 4; ++kb) {
        bfrag a = *(const bfrag*)&buf[c0 + lr][8 * lg + 32 * kb];
        bfrag b = *(const bfrag*)&xT[w0 + lr + 2][8 * lg + 32 * kb];
        acc2 = __builtin_amdgcn_mfma_f32_16x16x32_bf16(a, b, acc2, 0, 0, 0);
      }
#pragma unroll
      for (int e = 0; e < 4; ++e) {
        int c = c0 + 4 * lg + e;
        out[((size_t)n * C_ + c) * HW_ + h * W_ + w0 + lr] = sA[c] - acc2[e];
      }
    }
  }
}

// ---------------------------------------------------------------------------
extern "C" void kernel_launch(void* const* d_in, const int* in_sizes, int n_in,
                              void* d_out, int out_size, void* d_ws, size_t ws_size,
                              hipStream_t stream) {
  const float* x = (const float*)d_in[0];
  const float* p7 = (const float*)d_in[1];
  // d_in[2] (p8_w) cancels algebraically: t10 = t8 - (x + t8) = -x
  const float* p19 = (const float*)d_in[3];
  const float* cw = (const float*)d_in[4];
  float* ws = (float*)d_ws;
  float* out = (float*)d_out;

  ath_t7<<<dim3(H_, N_), 192, 0, stream>>>(x, p7, ws);
  ath_gram<<<2 * NKS * N_ + 42, 256, 0, stream>>>(x, cw, ws);
  ath_assemble<<<N_ * 28, 128, 0, stream>>>(p19, ws);
  ath_fused<<<dim3(H_, N_), 256, 0, stream>>>(x, ws, out);
}

// Round 15
// 46.645 us; speedup vs baseline: 1.2047x; 1.2047x over previous
//
#include <hip/hip_runtime.h>

typedef __attribute__((ext_vector_type(8))) short bfrag;   // 8 bf16 = 4 VGPR
typedef __attribute__((ext_vector_type(4))) float f32x4;

namespace {
constexpr int N_ = 16, C_ = 112, H_ = 48, W_ = 48, HW_ = 2304;
constexpr int NKS = 18;  // K-slices of 128 (18*128 = 2304)
// ws float offsets
constexpr int WS_T7 = 0;          // 768
constexpr int WS_A = 1024;        // 1792 -> 2816
constexpr int WS_WPACK = 40960;   // 3*112*128 bf16 = 21504 f -> 62464
constexpr int WS_GBF = 62464;     // 16*112*128 bf16 = 114688 f -> 177152
constexpr int WS_SPART = 177152;  // 18*16*112*128 f32 = 4128768 -> 4305920 (17.2 MB)
}

__device__ __forceinline__ float f4e(const float4& v, int e) {
  return e == 0 ? v.x : e == 1 ? v.y : e == 2 ? v.z : v.w;
}
__device__ __forceinline__ unsigned short f2bf(float f) {  // RNE
  unsigned u = __float_as_uint(f);
  return (unsigned short)((u + 0x7FFFu + ((u >> 16) & 1u)) >> 16);
}
__device__ __forceinline__ float bf2f(unsigned short s) {
  return __uint_as_float(((unsigned)s) << 16);
}

// ---------------------------------------------------------------------------
// K1: t7 as a 48-tap projection of x rows, coalesced: 12 consecutive lanes
// read one contiguous 192B row. t7[n,h'] = (1/112) sum_c dot(x[n,c,h',:], q),
// q[j] = sum_k p7[k][j+3-3k]; value lands at (h'+2)%48 (S3=+1,S6=+1 -> +2).
// grid (48, 16), 192 threads.
__global__ __launch_bounds__(192) void ath_t7(const float* __restrict__ x,
                                              const float* __restrict__ p7,
                                              float* __restrict__ ws) {
  const int h = blockIdx.x, n = blockIdx.y;
  const int tid = threadIdx.x;
  __shared__ float q[48];
  __shared__ float wred[3];
  if (tid < 48) {
    float s = 0.f;
#pragma unroll
    for (int k = 0; k < 3; ++k) {
      int wp = tid + 3 - 3 * k;
      if (wp >= 0 && wp < 48) s += p7[k * 48 + wp];
    }
    q[tid] = s;
  }
  __syncthreads();
  const int c16 = tid / 12, qq = tid - 12 * c16;
  const float qv0 = q[4 * qq], qv1 = q[4 * qq + 1];
  const float qv2 = q[4 * qq + 2], qv3 = q[4 * qq + 3];
  float d = 0.f;
#pragma unroll
  for (int p = 0; p < 7; ++p) {
    const int c = c16 + 16 * p;
    float4 v = *(const float4*)&x[((size_t)n * C_ + c) * HW_ + h * W_ + 4 * qq];
    d += v.x * qv0 + v.y * qv1 + v.z * qv2 + v.w * qv3;
  }
#pragma unroll
  for (int off = 32; off >= 1; off >>= 1) d += __shfl_xor(d, off);
  if ((tid & 63) == 0) wred[tid >> 6] = d;
  __syncthreads();
  if (tid == 0)
    ws[WS_T7 + n * H_ + (h + 2) % 48] =
        (wred[0] + wred[1] + wred[2]) * (1.0f / 112.0f);
}

// ---------------------------------------------------------------------------
// K2: Gram via MFMA, st17-augmented A (LDS) x raw-x B (register-prefetched),
// virtual t7 B-row for A'. Block = (n, ks, half): half owns ti = wv + 4*half.
// t17 recomputed per block from t7 (cheap). Tail blocks: wpack.
// grid 576 + 42, 256 threads.
__global__ __launch_bounds__(256) void ath_gram(const float* __restrict__ x,
                                                const float* __restrict__ cw,
                                                float* __restrict__ ws) {
  const int bid = blockIdx.x;
  const int tid = threadIdx.x;
  if (bid >= 2 * NKS * N_) {  // ---- wpack tail: bf16 [kx][o][i pad 128]
    int idx = (bid - 2 * NKS * N_) * 256 + tid;
    if (idx < 3 * 112 * 32) {
      int kx = idx / (112 * 32);
      int r = idx - kx * 112 * 32;
      int o = r >> 5;
      int i0 = (r & 31) * 4;
      unsigned short v[4];
#pragma unroll
      for (int e = 0; e < 4; ++e) {
        int i = i0 + e;
        v[e] = (i < 112) ? f2bf(cw[o * 336 + i * 3 + kx]) : (unsigned short)0;
      }
      unsigned short* wp = (unsigned short*)(ws + WS_WPACK);
      *(ushort4*)&wp[(kx * 112 + o) * 128 + i0] = make_ushort4(v[0], v[1], v[2], v[3]);
    }
    return;
  }
  const int half = bid & 1;
  const int ks = (bid >> 1) % NKS;
  const int n = bid / (2 * NKS);
  const int k0 = ks * 128;
  const int lane = tid & 63, wv = tid >> 6;
  const int lr = lane & 15, lg = lane >> 4;
  __shared__ __align__(16) unsigned short As[112][136];
  __shared__ __align__(16) unsigned short t7r[136];
  __shared__ float t7s[48];
  __shared__ float s17[8];
  if (tid < 48) t7s[tid] = ws[WS_T7 + n * H_ + tid];
  __syncthreads();
  if (tid < 7) {  // t17[kk] = (1/48) sum_h |t7pad[2kk+h-6]|
    float s = 0.f;
    for (int hh = 0; hh < 48; ++hh) {
      int j = 2 * tid + hh - 6;
      if (j >= 0 && j < 48) s += fabsf(t7s[j]);
    }
    s17[tid] = s * (1.0f / 48.0f);
  }
  if (tid >= 64 && tid < 192) t7r[tid - 64] = f2bf(t7s[(k0 + tid - 64) / 48]);
  if (tid >= 192 && tid < 200) t7r[128 + (tid - 192)] = 0;
  // prefetch B fragments into registers (no LDS dependency; overlaps)
  const int ti = wv + 4 * half;  // this wave's output column-group (0..7)
  bfrag breg[4];
  if (ti < 7) {
    const float* bp = &x[((size_t)n * C_ + 16 * ti + lr) * HW_ + k0 + 8 * lg];
#pragma unroll
    for (int kb = 0; kb < 4; ++kb) {
      float4 v0 = *(const float4*)(bp + 32 * kb);
      float4 v1 = *(const float4*)(bp + 32 * kb + 4);
      breg[kb][0] = (short)f2bf(v0.x); breg[kb][1] = (short)f2bf(v0.y);
      breg[kb][2] = (short)f2bf(v0.z); breg[kb][3] = (short)f2bf(v0.w);
      breg[kb][4] = (short)f2bf(v1.x); breg[kb][5] = (short)f2bf(v1.y);
      breg[kb][6] = (short)f2bf(v1.z); breg[kb][7] = (short)f2bf(v1.w);
    }
  }
  __syncthreads();  // s17/t7r visible to ALL waves before A staging reads s17
  // stage augmented A: As[c][p-k0] = bf16(x[c,p] + s17[(c+p)%7])
  const int kq = tid & 31, cg = tid >> 5;
  const int base7 = (k0 + 4 * kq) % 7;
#pragma unroll
  for (int r = 0; r < 14; ++r) {
    const int c = cg + 8 * r;
    float4 v = *(const float4*)&x[((size_t)n * C_ + c) * HW_ + k0 + 4 * kq];
    int cls0 = (base7 + c) % 7;
    unsigned short a4[4];
#pragma unroll
    for (int e = 0; e < 4; ++e) {
      int cl = cls0 + e;
      cl = (cl >= 7) ? cl - 7 : cl;
      a4[e] = f2bf(f4e(v, e) + s17[cl]);
    }
    *(ushort4*)&As[c][4 * kq] = make_ushort4(a4[0], a4[1], a4[2], a4[3]);
  }
  __syncthreads();
  if (ti == 7) {
    const bfrag zero8 = {0, 0, 0, 0, 0, 0, 0, 0};
#pragma unroll
    for (int kb = 0; kb < 4; ++kb)
      breg[kb] = (lr == 0) ? *(const bfrag*)&t7r[8 * lg + 32 * kb] : zero8;
  }
  f32x4 acc[7];
#pragma unroll
  for (int j = 0; j < 7; ++j) acc[j] = (f32x4){0.f, 0.f, 0.f, 0.f};
#pragma unroll
  for (int kb = 0; kb < 4; ++kb) {
#pragma unroll
    for (int tc = 0; tc < 7; ++tc) {
      bfrag a = *(const bfrag*)&As[16 * tc + lr][8 * lg + 32 * kb];
      acc[tc] = __builtin_amdgcn_mfma_f32_16x16x32_bf16(a, breg[kb], acc[tc], 0, 0, 0);
    }
  }
  float* sp = ws + WS_SPART + (size_t)(n * NKS + ks) * 14336;
#pragma unroll
  for (int tc = 0; tc < 7; ++tc)
#pragma unroll
    for (int e = 0; e < 4; ++e)
      sp[(16 * tc + 4 * lg + e) * 128 + 16 * ti + lr] = acc[tc][e];
}

// ---------------------------------------------------------------------------
// K3: reduce SPART -> Gbf (bf16, cols>=112 zero) + A'. grid N*28, 128 thr.
__global__ __launch_bounds__(128) void ath_assemble(const float* __restrict__ p19,
                                                    float* __restrict__ ws) {
  const int bid = blockIdx.x;
  const int n = bid / 28, g = bid % 28;
  const int tid = threadIdx.x;
  const int cloc = tid >> 5, q = tid & 31;
  const int c = 4 * g + cloc;
  const int i0 = 4 * q;
  float4 s = make_float4(0.f, 0.f, 0.f, 0.f);
#pragma unroll
  for (int ks = 0; ks < NKS; ++ks) {
    float4 t = *(const float4*)&ws[WS_SPART + (size_t)(n * NKS + ks) * 14336 + c * 128 + i0];
    s.x += t.x; s.y += t.y; s.z += t.z; s.w += t.w;
  }
  unsigned short* gb = (unsigned short*)(ws + WS_GBF);
  if (i0 < 112) {
    const float scale = 1.0f / (48.0f * sqrtf(112.0f));
    const float pc = p19[c];
    *(ushort4*)&gb[((size_t)n * C_ + c) * 128 + i0] =
        make_ushort4(f2bf(pc * s.x * scale), f2bf(pc * s.y * scale),
                     f2bf(pc * s.z * scale), f2bf(pc * s.w * scale));
  } else {
    *(ushort4*)&gb[((size_t)n * C_ + c) * 128 + i0] = make_ushort4(0, 0, 0, 0);
    if (i0 == 112) ws[WS_A + n * C_ + c] = p19[c] * s.x * (2.0f / 48.0f);
  }
}

// ---------------------------------------------------------------------------
// K4 fused via MFMA, LDS-stationary operands (R13 structure: stage loops
// between barriers, loads NOT held across the MFMA phase — reg-held prefetch
// pushed VGPR past the 128 cliff and cost a block/CU, R14 post-mortem).
// xT[52][136] bf16 transposed x-slab; buf[112][136] = wp slice kx, then Gbf.
// t13 in-place into xT. 21 16x16 tiles round-robin over 4 waves. LDS ~45 KB.
__global__ __launch_bounds__(256) void ath_fused(const float* __restrict__ x,
                                                 const float* __restrict__ ws,
                                                 float* __restrict__ out) {
  const int h = blockIdx.x, n = blockIdx.y;
  const int tid = threadIdx.x;
  const int lane = tid & 63, wv = tid >> 6;
  const int lr = lane & 15, lg = lane >> 4;
  __shared__ __align__(16) unsigned short xT[52][136];
  __shared__ __align__(16) unsigned short buf[112][136];
  __shared__ float sA[112];
  const float* xb = x + (size_t)n * C_ * HW_ + h * W_;
  const unsigned short* wp = (const unsigned short*)(ws + WS_WPACK);
  const unsigned short* gb = (const unsigned short*)(ws + WS_GBF) + (size_t)n * C_ * 128;
  // zero pads
  for (int idx = tid; idx < 52 * 24; idx += 256) {
    int r2 = idx / 24, cc = 112 + idx % 24;
    xT[r2][cc] = 0;
  }
  for (int idx = tid; idx < 4 * 112; idx += 256) {
    int rr = idx / 112;
    int r2 = (rr < 2) ? rr : 48 + rr;
    xT[r2][idx % 112] = 0;
  }
  if (tid < 112) sA[tid] = ws[WS_A + n * C_ + tid];
  // stage x -> xT bf16 (transpose, packed 2-channel u32 writes)
  for (int idx = tid; idx < 672; idx += 256) {
    int i2 = idx / 12, q = idx - i2 * 12;
    float4 a = *(const float4*)&xb[(size_t)(2 * i2) * HW_ + 4 * q];
    float4 b = *(const float4*)&xb[(size_t)(2 * i2 + 1) * HW_ + 4 * q];
#pragma unroll
    for (int e = 0; e < 4; ++e) {
      unsigned pk = (unsigned)f2bf(f4e(a, e)) | ((unsigned)f2bf(f4e(b, e)) << 16);
      *(unsigned*)&xT[4 * q + 2 + e][2 * i2] = pk;
    }
  }
  // stage wp slice 0 into buf
  for (int idx = tid; idx < 1792; idx += 256) {
    int row = idx >> 4, cq = idx & 15;
    *(float4*)&buf[row][cq * 8] = *(const float4*)&wp[(size_t)row * 128 + cq * 8];
  }
  __syncthreads();

  // ---- conv phase, kx-outer, accs persistent
  f32x4 acc[6];
#pragma unroll
  for (int j = 0; j < 6; ++j) acc[j] = (f32x4){0.f, 0.f, 0.f, 0.f};
  for (int kx = 0; kx < 3; ++kx) {
    if (kx) {
      __syncthreads();  // drain buf reads from previous kx
      for (int idx = tid; idx < 1792; idx += 256) {
        int row = idx >> 4, cq = idx & 15;
        *(float4*)&buf[row][cq * 8] =
            *(const float4*)&wp[(size_t)(kx * 112 + row) * 128 + cq * 8];
      }
      __syncthreads();
    }
#pragma unroll
    for (int j = 0; j < 6; ++j) {
      int t = wv + 4 * j;
      if (t < 21) {
        int m = t / 3, nt = t - 3 * m;
        int o0 = m * 16, w0 = nt * 16;
#pragma unroll
        for (int kb = 0; kb < 4; ++kb) {
          bfrag a = *(const bfrag*)&buf[o0 + lr][8 * lg + 32 * kb];
          bfrag b = *(const bfrag*)&xT[w0 + lr + 2 * kx][8 * lg + 32 * kb];
          acc[j] = __builtin_amdgcn_mfma_f32_16x16x32_bf16(a, b, acc[j], 0, 0, 0);
        }
      }
    }
  }
  // t13 = max(-conv, x)
  unsigned short tv[6][4];
#pragma unroll
  for (int j = 0; j < 6; ++j) {
    int t = wv + 4 * j;
    if (t < 21) {
      int m = t / 3, nt = t - 3 * m;
      int o0 = m * 16, w0 = nt * 16;
#pragma unroll
      for (int e = 0; e < 4; ++e) {
        float xv = bf2f(xT[w0 + lr + 2][o0 + 4 * lg + e]);
        tv[j][e] = f2bf(fmaxf(-acc[j][e], xv));
      }
    }
  }
  __syncthreads();  // all conv reads of xT/buf complete
  // write t13 into xT; stage Gbf into buf
#pragma unroll
  for (int j = 0; j < 6; ++j) {
    int t = wv + 4 * j;
    if (t < 21) {
      int m = t / 3, nt = t - 3 * m;
      int o0 = m * 16, w0 = nt * 16;
      unsigned pk0 = (unsigned)tv[j][0] | ((unsigned)tv[j][1] << 16);
      unsigned pk1 = (unsigned)tv[j][2] | ((unsigned)tv[j][3] << 16);
      *(unsigned*)&xT[w0 + lr + 2][o0 + 4 * lg] = pk0;
      *(unsigned*)&xT[w0 + lr + 2][o0 + 4 * lg + 2] = pk1;
    }
  }
  for (int idx = tid; idx < 1792; idx += 256) {
    int row = idx >> 4, cq = idx & 15;
    *(float4*)&buf[row][cq * 8] = *(const float4*)&gb[(size_t)row * 128 + cq * 8];
  }
  __syncthreads();  // t13 + Gbf visible

  // ---- final GEMM: out[c][w] = A'[c] - sum_i G'[c][i] * t13[i][w]
#pragma unroll
  for (int j = 0; j < 6; ++j) {
    int t = wv + 4 * j;
    if (t < 21) {
      int m = t / 3, nt = t - 3 * m;
      int c0 = m * 16, w0 = nt * 16;
      f32x4 acc2 = {0.f, 0.f, 0.f, 0.f};
#pragma unroll
      for (int kb = 0; kb < 4; ++kb) {
        bfrag a = *(const bfrag*)&buf[c0 + lr][8 * lg + 32 * kb];
        bfrag b = *(const bfrag*)&xT[w0 + lr + 2][8 * lg + 32 * kb];
        acc2 = __builtin_amdgcn_mfma_f32_16x16x32_bf16(a, b, acc2, 0, 0, 0);
      }
#pragma unroll
      for (int e = 0; e < 4; ++e) {
        int c = c0 + 4 * lg + e;
        out[((size_t)n * C_ + c) * HW_ + h * W_ + w0 + lr] = sA[c] - acc2[e];
      }
    }
  }
}

// ---------------------------------------------------------------------------
extern "C" void kernel_launch(void* const* d_in, const int* in_sizes, int n_in,
                              void* d_out, int out_size, void* d_ws, size_t ws_size,
                              hipStream_t stream) {
  const float* x = (const float*)d_in[0];
  const float* p7 = (const float*)d_in[1];
  // d_in[2] (p8_w) cancels algebraically: t10 = t8 - (x + t8) = -x
  const float* p19 = (const float*)d_in[3];
  const float* cw = (const float*)d_in[4];
  float* ws = (float*)d_ws;
  float* out = (float*)d_out;

  ath_t7<<<dim3(H_, N_), 192, 0, stream>>>(x, p7, ws);
  ath_gram<<<2 * NKS * N_ + 42, 256, 0, stream>>>(x, cw, ws);
  ath_assemble<<<N_ * 28, 128, 0, stream>>>(p19, ws);
  ath_fused<<<dim3(H_, N_), 256, 0, stream>>>(x, ws, out);
}

// Round 16
// 45.465 us; speedup vs baseline: 1.2360x; 1.0260x over previous
//
#include <hip/hip_runtime.h>

typedef __attribute__((ext_vector_type(8))) short bfrag;   // 8 bf16 = 4 VGPR
typedef __attribute__((ext_vector_type(4))) float f32x4;

namespace {
constexpr int N_ = 16, C_ = 112, H_ = 48, W_ = 48, HW_ = 2304;
constexpr int NKS = 18;  // K-slices of 128 (18*128 = 2304)
// ws float offsets
constexpr int WS_T7 = 0;          // 768
constexpr int WS_A = 1024;        // 1792 -> 2816
constexpr int WS_WPACK = 40960;   // 3*112*128 bf16 = 21504 f -> 62464
constexpr int WS_GBF = 62464;     // 16*112*128 bf16 = 114688 f -> 177152
constexpr int WS_SPART = 177152;  // bf16 partials: 18*16*112*128*2B = 8.25MB
}

__device__ __forceinline__ float f4e(const float4& v, int e) {
  return e == 0 ? v.x : e == 1 ? v.y : e == 2 ? v.z : v.w;
}
__device__ __forceinline__ unsigned short f2bf(float f) {  // RNE
  unsigned u = __float_as_uint(f);
  return (unsigned short)((u + 0x7FFFu + ((u >> 16) & 1u)) >> 16);
}
__device__ __forceinline__ float bf2f(unsigned short s) {
  return __uint_as_float(((unsigned)s) << 16);
}

// ---------------------------------------------------------------------------
// K1: t7 as a 48-tap projection of x rows, coalesced: 12 consecutive lanes
// read one contiguous 192B row. t7[n,h'] = (1/112) sum_c dot(x[n,c,h',:], q),
// q[j] = sum_k p7[k][j+3-3k]; value lands at (h'+2)%48 (S3=+1,S6=+1 -> +2).
// grid (48, 16), 192 threads.
__global__ __launch_bounds__(192) void ath_t7(const float* __restrict__ x,
                                              const float* __restrict__ p7,
                                              float* __restrict__ ws) {
  const int h = blockIdx.x, n = blockIdx.y;
  const int tid = threadIdx.x;
  __shared__ float q[48];
  __shared__ float wred[3];
  if (tid < 48) {
    float s = 0.f;
#pragma unroll
    for (int k = 0; k < 3; ++k) {
      int wp = tid + 3 - 3 * k;
      if (wp >= 0 && wp < 48) s += p7[k * 48 + wp];
    }
    q[tid] = s;
  }
  __syncthreads();
  const int c16 = tid / 12, qq = tid - 12 * c16;
  const float qv0 = q[4 * qq], qv1 = q[4 * qq + 1];
  const float qv2 = q[4 * qq + 2], qv3 = q[4 * qq + 3];
  float d = 0.f;
#pragma unroll
  for (int p = 0; p < 7; ++p) {
    const int c = c16 + 16 * p;
    float4 v = *(const float4*)&x[((size_t)n * C_ + c) * HW_ + h * W_ + 4 * qq];
    d += v.x * qv0 + v.y * qv1 + v.z * qv2 + v.w * qv3;
  }
#pragma unroll
  for (int off = 32; off >= 1; off >>= 1) d += __shfl_xor(d, off);
  if ((tid & 63) == 0) wred[tid >> 6] = d;
  __syncthreads();
  if (tid == 0)
    ws[WS_T7 + n * H_ + (h + 2) % 48] =
        (wred[0] + wred[1] + wred[2]) * (1.0f / 112.0f);
}

// ---------------------------------------------------------------------------
// K2: Gram via MFMA, st17-augmented A (LDS) x raw-x B (register-prefetched),
// virtual t7 B-row for A'. Block = (n, ks, half): half owns ti = wv + 4*half.
// t17 recomputed per block from t7 (cheap). SPART stored as bf16 (error
// budget: ~1 abs in S -> ~4e-5 at output scale; 5x headroom remains).
// Tail blocks: wpack. grid 576 + 42, 256 threads.
__global__ __launch_bounds__(256) void ath_gram(const float* __restrict__ x,
                                                const float* __restrict__ cw,
                                                float* __restrict__ ws) {
  const int bid = blockIdx.x;
  const int tid = threadIdx.x;
  if (bid >= 2 * NKS * N_) {  // ---- wpack tail: bf16 [kx][o][i pad 128]
    int idx = (bid - 2 * NKS * N_) * 256 + tid;
    if (idx < 3 * 112 * 32) {
      int kx = idx / (112 * 32);
      int r = idx - kx * 112 * 32;
      int o = r >> 5;
      int i0 = (r & 31) * 4;
      unsigned short v[4];
#pragma unroll
      for (int e = 0; e < 4; ++e) {
        int i = i0 + e;
        v[e] = (i < 112) ? f2bf(cw[o * 336 + i * 3 + kx]) : (unsigned short)0;
      }
      unsigned short* wp = (unsigned short*)(ws + WS_WPACK);
      *(ushort4*)&wp[(kx * 112 + o) * 128 + i0] = make_ushort4(v[0], v[1], v[2], v[3]);
    }
    return;
  }
  const int half = bid & 1;
  const int ks = (bid >> 1) % NKS;
  const int n = bid / (2 * NKS);
  const int k0 = ks * 128;
  const int lane = tid & 63, wv = tid >> 6;
  const int lr = lane & 15, lg = lane >> 4;
  __shared__ __align__(16) unsigned short As[112][136];
  __shared__ __align__(16) unsigned short t7r[136];
  __shared__ float t7s[48];
  __shared__ float s17[8];
  if (tid < 48) t7s[tid] = ws[WS_T7 + n * H_ + tid];
  __syncthreads();
  if (tid < 7) {  // t17[kk] = (1/48) sum_h |t7pad[2kk+h-6]|
    float s = 0.f;
    for (int hh = 0; hh < 48; ++hh) {
      int j = 2 * tid + hh - 6;
      if (j >= 0 && j < 48) s += fabsf(t7s[j]);
    }
    s17[tid] = s * (1.0f / 48.0f);
  }
  if (tid >= 64 && tid < 192) t7r[tid - 64] = f2bf(t7s[(k0 + tid - 64) / 48]);
  if (tid >= 192 && tid < 200) t7r[128 + (tid - 192)] = 0;
  // prefetch B fragments into registers (no LDS dependency; overlaps)
  const int ti = wv + 4 * half;  // this wave's output column-group (0..7)
  bfrag breg[4];
  if (ti < 7) {
    const float* bp = &x[((size_t)n * C_ + 16 * ti + lr) * HW_ + k0 + 8 * lg];
#pragma unroll
    for (int kb = 0; kb < 4; ++kb) {
      float4 v0 = *(const float4*)(bp + 32 * kb);
      float4 v1 = *(const float4*)(bp + 32 * kb + 4);
      breg[kb][0] = (short)f2bf(v0.x); breg[kb][1] = (short)f2bf(v0.y);
      breg[kb][2] = (short)f2bf(v0.z); breg[kb][3] = (short)f2bf(v0.w);
      breg[kb][4] = (short)f2bf(v1.x); breg[kb][5] = (short)f2bf(v1.y);
      breg[kb][6] = (short)f2bf(v1.z); breg[kb][7] = (short)f2bf(v1.w);
    }
  }
  __syncthreads();  // s17/t7r visible to ALL waves before A staging reads s17
  // stage augmented A: As[c][p-k0] = bf16(x[c,p] + s17[(c+p)%7])
  const int kq = tid & 31, cg = tid >> 5;
  const int base7 = (k0 + 4 * kq) % 7;
#pragma unroll
  for (int r = 0; r < 14; ++r) {
    const int c = cg + 8 * r;
    float4 v = *(const float4*)&x[((size_t)n * C_ + c) * HW_ + k0 + 4 * kq];
    int cls0 = (base7 + c) % 7;
    unsigned short a4[4];
#pragma unroll
    for (int e = 0; e < 4; ++e) {
      int cl = cls0 + e;
      cl = (cl >= 7) ? cl - 7 : cl;
      a4[e] = f2bf(f4e(v, e) + s17[cl]);
    }
    *(ushort4*)&As[c][4 * kq] = make_ushort4(a4[0], a4[1], a4[2], a4[3]);
  }
  __syncthreads();
  if (ti == 7) {
    const bfrag zero8 = {0, 0, 0, 0, 0, 0, 0, 0};
#pragma unroll
    for (int kb = 0; kb < 4; ++kb)
      breg[kb] = (lr == 0) ? *(const bfrag*)&t7r[8 * lg + 32 * kb] : zero8;
  }
  f32x4 acc[7];
#pragma unroll
  for (int j = 0; j < 7; ++j) acc[j] = (f32x4){0.f, 0.f, 0.f, 0.f};
#pragma unroll
  for (int kb = 0; kb < 4; ++kb) {
#pragma unroll
    for (int tc = 0; tc < 7; ++tc) {
      bfrag a = *(const bfrag*)&As[16 * tc + lr][8 * lg + 32 * kb];
      acc[tc] = __builtin_amdgcn_mfma_f32_16x16x32_bf16(a, breg[kb], acc[tc], 0, 0, 0);
    }
  }
  unsigned short* sp =
      (unsigned short*)(ws + WS_SPART) + (size_t)(n * NKS + ks) * 14336;
#pragma unroll
  for (int tc = 0; tc < 7; ++tc)
#pragma unroll
    for (int e = 0; e < 4; ++e)
      sp[(16 * tc + 4 * lg + e) * 128 + 16 * ti + lr] = f2bf(acc[tc][e]);
}

// ---------------------------------------------------------------------------
// K3: reduce bf16 SPART -> Gbf (bf16, cols>=112 zero) + A'. f32 accumulate.
// grid N*28, 128 thr (each lane sums 4 cols x 18 slices; 8B loads).
__global__ __launch_bounds__(128) void ath_assemble(const float* __restrict__ p19,
                                                    float* __restrict__ ws) {
  const int bid = blockIdx.x;
  const int n = bid / 28, g = bid % 28;
  const int tid = threadIdx.x;
  const int cloc = tid >> 5, q = tid & 31;
  const int c = 4 * g + cloc;
  const int i0 = 4 * q;
  const unsigned short* spb = (const unsigned short*)(ws + WS_SPART);
  float s0 = 0.f, s1 = 0.f, s2 = 0.f, s3 = 0.f;
#pragma unroll
  for (int ks = 0; ks < NKS; ++ks) {
    ushort4 t = *(const ushort4*)&spb[(size_t)(n * NKS + ks) * 14336 + c * 128 + i0];
    s0 += bf2f(t.x); s1 += bf2f(t.y); s2 += bf2f(t.z); s3 += bf2f(t.w);
  }
  unsigned short* gb = (unsigned short*)(ws + WS_GBF);
  if (i0 < 112) {
    const float scale = 1.0f / (48.0f * sqrtf(112.0f));
    const float pc = p19[c];
    *(ushort4*)&gb[((size_t)n * C_ + c) * 128 + i0] =
        make_ushort4(f2bf(pc * s0 * scale), f2bf(pc * s1 * scale),
                     f2bf(pc * s2 * scale), f2bf(pc * s3 * scale));
  } else {
    *(ushort4*)&gb[((size_t)n * C_ + c) * 128 + i0] = make_ushort4(0, 0, 0, 0);
    if (i0 == 112) ws[WS_A + n * C_ + c] = p19[c] * s0 * (2.0f / 48.0f);
  }
}

// ---------------------------------------------------------------------------
// K4 fused via MFMA, LDS-stationary operands (R13 structure: stage loops
// between barriers, loads NOT held across the MFMA phase — reg-held prefetch
// pushed VGPR past the 128 cliff and cost a block/CU, R14 post-mortem).
// xT[52][136] bf16 transposed x-slab; buf[112][136] = wp slice kx, then Gbf.
// t13 in-place into xT. 21 16x16 tiles round-robin over 4 waves. LDS ~45 KB.
__global__ __launch_bounds__(256) void ath_fused(const float* __restrict__ x,
                                                 const float* __restrict__ ws,
                                                 float* __restrict__ out) {
  const int h = blockIdx.x, n = blockIdx.y;
  const int tid = threadIdx.x;
  const int lane = tid & 63, wv = tid >> 6;
  const int lr = lane & 15, lg = lane >> 4;
  __shared__ __align__(16) unsigned short xT[52][136];
  __shared__ __align__(16) unsigned short buf[112][136];
  __shared__ float sA[112];
  const float* xb = x + (size_t)n * C_ * HW_ + h * W_;
  const unsigned short* wp = (const unsigned short*)(ws + WS_WPACK);
  const unsigned short* gb = (const unsigned short*)(ws + WS_GBF) + (size_t)n * C_ * 128;
  // zero pads
  for (int idx = tid; idx < 52 * 24; idx += 256) {
    int r2 = idx / 24, cc = 112 + idx % 24;
    xT[r2][cc] = 0;
  }
  for (int idx = tid; idx < 4 * 112; idx += 256) {
    int rr = idx / 112;
    int r2 = (rr < 2) ? rr : 48 + rr;
    xT[r2][idx % 112] = 0;
  }
  if (tid < 112) sA[tid] = ws[WS_A + n * C_ + tid];
  // stage x -> xT bf16 (transpose, packed 2-channel u32 writes)
  for (int idx = tid; idx < 672; idx += 256) {
    int i2 = idx / 12, q = idx - i2 * 12;
    float4 a = *(const float4*)&xb[(size_t)(2 * i2) * HW_ + 4 * q];
    float4 b = *(const float4*)&xb[(size_t)(2 * i2 + 1) * HW_ + 4 * q];
#pragma unroll
    for (int e = 0; e < 4; ++e) {
      unsigned pk = (unsigned)f2bf(f4e(a, e)) | ((unsigned)f2bf(f4e(b, e)) << 16);
      *(unsigned*)&xT[4 * q + 2 + e][2 * i2] = pk;
    }
  }
  // stage wp slice 0 into buf
  for (int idx = tid; idx < 1792; idx += 256) {
    int row = idx >> 4, cq = idx & 15;
    *(float4*)&buf[row][cq * 8] = *(const float4*)&wp[(size_t)row * 128 + cq * 8];
  }
  __syncthreads();

  // ---- conv phase, kx-outer, accs persistent
  f32x4 acc[6];
#pragma unroll
  for (int j = 0; j < 6; ++j) acc[j] = (f32x4){0.f, 0.f, 0.f, 0.f};
  for (int kx = 0; kx < 3; ++kx) {
    if (kx) {
      __syncthreads();  // drain buf reads from previous kx
      for (int idx = tid; idx < 1792; idx += 256) {
        int row = idx >> 4, cq = idx & 15;
        *(float4*)&buf[row][cq * 8] =
            *(const float4*)&wp[(size_t)(kx * 112 + row) * 128 + cq * 8];
      }
      __syncthreads();
    }
#pragma unroll
    for (int j = 0; j < 6; ++j) {
      int t = wv + 4 * j;
      if (t < 21) {
        int m = t / 3, nt = t - 3 * m;
        int o0 = m * 16, w0 = nt * 16;
#pragma unroll
        for (int kb = 0; kb < 4; ++kb) {
          bfrag a = *(const bfrag*)&buf[o0 + lr][8 * lg + 32 * kb];
          bfrag b = *(const bfrag*)&xT[w0 + lr + 2 * kx][8 * lg + 32 * kb];
          acc[j] = __builtin_amdgcn_mfma_f32_16x16x32_bf16(a, b, acc[j], 0, 0, 0);
        }
      }
    }
  }
  // t13 = max(-conv, x)
  unsigned short tv[6][4];
#pragma unroll
  for (int j = 0; j < 6; ++j) {
    int t = wv + 4 * j;
    if (t < 21) {
      int m = t / 3, nt = t - 3 * m;
      int o0 = m * 16, w0 = nt * 16;
#pragma unroll
      for (int e = 0; e < 4; ++e) {
        float xv = bf2f(xT[w0 + lr + 2][o0 + 4 * lg + e]);
        tv[j][e] = f2bf(fmaxf(-acc[j][e], xv));
      }
    }
  }
  __syncthreads();  // all conv reads of xT/buf complete
  // write t13 into xT; stage Gbf into buf
#pragma unroll
  for (int j = 0; j < 6; ++j) {
    int t = wv + 4 * j;
    if (t < 21) {
      int m = t / 3, nt = t - 3 * m;
      int o0 = m * 16, w0 = nt * 16;
      unsigned pk0 = (unsigned)tv[j][0] | ((unsigned)tv[j][1] << 16);
      unsigned pk1 = (unsigned)tv[j][2] | ((unsigned)tv[j][3] << 16);
      *(unsigned*)&xT[w0 + lr + 2][o0 + 4 * lg] = pk0;
      *(unsigned*)&xT[w0 + lr + 2][o0 + 4 * lg + 2] = pk1;
    }
  }
  for (int idx = tid; idx < 1792; idx += 256) {
    int row = idx >> 4, cq = idx & 15;
    *(float4*)&buf[row][cq * 8] = *(const float4*)&gb[(size_t)row * 128 + cq * 8];
  }
  __syncthreads();  // t13 + Gbf visible

  // ---- final GEMM: out[c][w] = A'[c] - sum_i G'[c][i] * t13[i][w]
#pragma unroll
  for (int j = 0; j < 6; ++j) {
    int t = wv + 4 * j;
    if (t < 21) {
      int m = t / 3, nt = t - 3 * m;
      int c0 = m * 16, w0 = nt * 16;
      f32x4 acc2 = {0.f, 0.f, 0.f, 0.f};
#pragma unroll
      for (int kb = 0; kb < 4; ++kb) {
        bfrag a = *(const bfrag*)&buf[c0 + lr][8 * lg + 32 * kb];
        bfrag b = *(const bfrag*)&xT[w0 + lr + 2][8 * lg + 32 * kb];
        acc2 = __builtin_amdgcn_mfma_f32_16x16x32_bf16(a, b, acc2, 0, 0, 0);
      }
#pragma unroll
      for (int e = 0; e < 4; ++e) {
        int c = c0 + 4 * lg + e;
        out[((size_t)n * C_ + c) * HW_ + h * W_ + w0 + lr] = sA[c] - acc2[e];
      }
    }
  }
}

// ---------------------------------------------------------------------------
extern "C" void kernel_launch(void* const* d_in, const int* in_sizes, int n_in,
                              void* d_out, int out_size, void* d_ws, size_t ws_size,
                              hipStream_t stream) {
  const float* x = (const float*)d_in[0];
  const float* p7 = (const float*)d_in[1];
  // d_in[2] (p8_w) cancels algebraically: t10 = t8 - (x + t8) = -x
  const float* p19 = (const float*)d_in[3];
  const float* cw = (const float*)d_in[4];
  float* ws = (float*)d_ws;
  float* out = (float*)d_out;

  ath_t7<<<dim3(H_, N_), 192, 0, stream>>>(x, p7, ws);
  ath_gram<<<2 * NKS * N_ + 42, 256, 0, stream>>>(x, cw, ws);
  ath_assemble<<<N_ * 28, 128, 0, stream>>>(p19, ws);
  ath_fused<<<dim3(H_, N_), 256, 0, stream>>>(x, ws, out);
}

// Round 17
// 45.186 us; speedup vs baseline: 1.2436x; 1.0062x over previous
//
#include <hip/hip_runtime.h>
#include <hip/hip_cooperative_groups.h>

namespace cg = cooperative_groups;

typedef __attribute__((ext_vector_type(8))) short bfrag;   // 8 bf16 = 4 VGPR
typedef __attribute__((ext_vector_type(4))) float f32x4;

namespace {
constexpr int N_ = 16, C_ = 112, H_ = 48, W_ = 48, HW_ = 2304;
constexpr int NKS = 18;  // K-slices of 128 (18*128 = 2304)
// ws float offsets
constexpr int WS_T7 = 0;          // 768
constexpr int WS_A = 1024;        // 1792 -> 2816
constexpr int WS_WPACK = 40960;   // 3*112*128 bf16 = 21504 f -> 62464
constexpr int WS_GBF = 62464;     // 16*112*128 bf16 = 114688 f -> 177152
constexpr int WS_SPART = 177152;  // bf16 partials: 18*16*112*128*2B = 8.25MB
}

__device__ __forceinline__ float f4e(const float4& v, int e) {
  return e == 0 ? v.x : e == 1 ? v.y : e == 2 ? v.z : v.w;
}
__device__ __forceinline__ unsigned short f2bf(float f) {  // RNE
  unsigned u = __float_as_uint(f);
  return (unsigned short)((u + 0x7FFFu + ((u >> 16) & 1u)) >> 16);
}
__device__ __forceinline__ float bf2f(unsigned short s) {
  return __uint_as_float(((unsigned)s) << 16);
}

// ===========================================================================
// MEGA: all 4 phases in one cooperative kernel. grid 768 x 256.
// LDS union: phase1 {q,wred}; phase2 {As,t7r,t7s,s17}; phase3/4 {xT,buf,sA}.
// ===========================================================================
__global__ __launch_bounds__(256, 3) void ath_mega(
    const float* __restrict__ x, const float* __restrict__ p7,
    const float* __restrict__ p19, const float* __restrict__ cw,
    float* __restrict__ ws, float* __restrict__ out) {
  cg::grid_group grid = cg::this_grid();
  const int bid = blockIdx.x;  // 0..767
  const int tid = threadIdx.x;
  const int lane = tid & 63, wv = tid >> 6;
  const int lr = lane & 15, lg = lane >> 4;
  __shared__ __align__(16) unsigned char smem[45056];

  // ============ phase 1: t7 (768 items: h = bid%48, n = bid/48) ============
  {
    float* q = (float*)smem;
    float* wred = (float*)(smem + 192);
    const int h = bid % 48, n = bid / 48;
    if (tid < 48) {
      float s = 0.f;
#pragma unroll
      for (int k = 0; k < 3; ++k) {
        int wp = tid + 3 - 3 * k;
        if (wp >= 0 && wp < 48) s += p7[k * 48 + wp];
      }
      q[tid] = s;
    }
    __syncthreads();
    float d = 0.f;
    if (tid < 192) {
      const int c16 = tid / 12, qq = tid - 12 * c16;
      const float qv0 = q[4 * qq], qv1 = q[4 * qq + 1];
      const float qv2 = q[4 * qq + 2], qv3 = q[4 * qq + 3];
#pragma unroll
      for (int p = 0; p < 7; ++p) {
        const int c = c16 + 16 * p;
        float4 v = *(const float4*)&x[((size_t)n * C_ + c) * HW_ + h * W_ + 4 * qq];
        d += v.x * qv0 + v.y * qv1 + v.z * qv2 + v.w * qv3;
      }
    }
#pragma unroll
    for (int off = 32; off >= 1; off >>= 1) d += __shfl_xor(d, off);
    if ((tid & 63) == 0 && tid < 192) wred[tid >> 6] = d;
    __syncthreads();
    if (tid == 0)
      ws[WS_T7 + (bid / 48) * H_ + ((bid % 48) + 2) % 48] =
          (wred[0] + wred[1] + wred[2]) * (1.0f / 112.0f);
  }
  grid.sync();

  // ============ phase 2: gram (576) + wpack (42) ============
  if (bid < 2 * NKS * N_) {
    unsigned short(*As)[136] = (unsigned short(*)[136])smem;
    unsigned short* t7r = (unsigned short*)(smem + 30464);
    float* t7s = (float*)(smem + 30736);
    float* s17 = (float*)(smem + 30928);
    const int half = bid & 1;
    const int ks = (bid >> 1) % NKS;
    const int n = bid / (2 * NKS);
    const int k0 = ks * 128;
    if (tid < 48) t7s[tid] = ws[WS_T7 + n * H_ + tid];
    __syncthreads();
    if (tid < 7) {  // t17[kk] = (1/48) sum_h |t7pad[2kk+h-6]|
      float s = 0.f;
      for (int hh = 0; hh < 48; ++hh) {
        int j = 2 * tid + hh - 6;
        if (j >= 0 && j < 48) s += fabsf(t7s[j]);
      }
      s17[tid] = s * (1.0f / 48.0f);
    }
    if (tid >= 64 && tid < 192) t7r[tid - 64] = f2bf(t7s[(k0 + tid - 64) / 48]);
    if (tid >= 192 && tid < 200) t7r[128 + (tid - 192)] = 0;
    // prefetch B fragments into registers (no LDS dependency; overlaps)
    const int ti = wv + 4 * half;
    bfrag breg[4];
    if (ti < 7) {
      const float* bp = &x[((size_t)n * C_ + 16 * ti + lr) * HW_ + k0 + 8 * lg];
#pragma unroll
      for (int kb = 0; kb < 4; ++kb) {
        float4 v0 = *(const float4*)(bp + 32 * kb);
        float4 v1 = *(const float4*)(bp + 32 * kb + 4);
        breg[kb][0] = (short)f2bf(v0.x); breg[kb][1] = (short)f2bf(v0.y);
        breg[kb][2] = (short)f2bf(v0.z); breg[kb][3] = (short)f2bf(v0.w);
        breg[kb][4] = (short)f2bf(v1.x); breg[kb][5] = (short)f2bf(v1.y);
        breg[kb][6] = (short)f2bf(v1.z); breg[kb][7] = (short)f2bf(v1.w);
      }
    }
    __syncthreads();  // s17/t7r visible before A staging reads s17
    const int kq = tid & 31, cg2 = tid >> 5;
    const int base7 = (k0 + 4 * kq) % 7;
#pragma unroll
    for (int r = 0; r < 14; ++r) {
      const int c = cg2 + 8 * r;
      float4 v = *(const float4*)&x[((size_t)n * C_ + c) * HW_ + k0 + 4 * kq];
      int cls0 = (base7 + c) % 7;
      unsigned short a4[4];
#pragma unroll
      for (int e = 0; e < 4; ++e) {
        int cl = cls0 + e;
        cl = (cl >= 7) ? cl - 7 : cl;
        a4[e] = f2bf(f4e(v, e) + s17[cl]);
      }
      *(ushort4*)&As[c][4 * kq] = make_ushort4(a4[0], a4[1], a4[2], a4[3]);
    }
    __syncthreads();
    if (ti == 7) {
      const bfrag zero8 = {0, 0, 0, 0, 0, 0, 0, 0};
#pragma unroll
      for (int kb = 0; kb < 4; ++kb)
        breg[kb] = (lr == 0) ? *(const bfrag*)&t7r[8 * lg + 32 * kb] : zero8;
    }
    f32x4 acc[7];
#pragma unroll
    for (int j = 0; j < 7; ++j) acc[j] = (f32x4){0.f, 0.f, 0.f, 0.f};
#pragma unroll
    for (int kb = 0; kb < 4; ++kb) {
#pragma unroll
      for (int tc = 0; tc < 7; ++tc) {
        bfrag a = *(const bfrag*)&As[16 * tc + lr][8 * lg + 32 * kb];
        acc[tc] = __builtin_amdgcn_mfma_f32_16x16x32_bf16(a, breg[kb], acc[tc], 0, 0, 0);
      }
    }
    unsigned short* sp =
        (unsigned short*)(ws + WS_SPART) + (size_t)(n * NKS + ks) * 14336;
#pragma unroll
    for (int tc = 0; tc < 7; ++tc)
#pragma unroll
      for (int e = 0; e < 4; ++e)
        sp[(16 * tc + 4 * lg + e) * 128 + 16 * ti + lr] = f2bf(acc[tc][e]);
  } else if (bid < 2 * NKS * N_ + 42) {  // wpack
    int idx = (bid - 2 * NKS * N_) * 256 + tid;
    if (idx < 3 * 112 * 32) {
      int kx = idx / (112 * 32);
      int r = idx - kx * 112 * 32;
      int o = r >> 5;
      int i0 = (r & 31) * 4;
      unsigned short v[4];
#pragma unroll
      for (int e = 0; e < 4; ++e) {
        int i = i0 + e;
        v[e] = (i < 112) ? f2bf(cw[o * 336 + i * 3 + kx]) : (unsigned short)0;
      }
      unsigned short* wp = (unsigned short*)(ws + WS_WPACK);
      *(ushort4*)&wp[(kx * 112 + o) * 128 + i0] = make_ushort4(v[0], v[1], v[2], v[3]);
    }
  }
  grid.sync();

  // ============ phase 3: assemble (thin, 75 thr/block) || fused stage+conv
  const int h = bid % 48, n = bid / 48;
  unsigned short(*xT)[136] = (unsigned short(*)[136])smem;
  unsigned short(*buf)[136] = (unsigned short(*)[136])(smem + 14144);
  float* sA = (float*)(smem + 44608);
  const float* xb = x + (size_t)n * C_ * HW_ + h * W_;
  const unsigned short* wp = (const unsigned short*)(ws + WS_WPACK);
  const unsigned short* gb =
      (const unsigned short*)(ws + WS_GBF) + (size_t)n * C_ * 128;
  {
    // fused staging: zero pads, xT transpose, wp slice 0 into buf
    for (int idx = tid; idx < 52 * 24; idx += 256) {
      int r2 = idx / 24, cc = 112 + idx % 24;
      xT[r2][cc] = 0;
    }
    for (int idx = tid; idx < 4 * 112; idx += 256) {
      int rr = idx / 112;
      int r2 = (rr < 2) ? rr : 48 + rr;
      xT[r2][idx % 112] = 0;
    }
    for (int idx = tid; idx < 672; idx += 256) {
      int i2 = idx / 12, q = idx - i2 * 12;
      float4 a = *(const float4*)&xb[(size_t)(2 * i2) * HW_ + 4 * q];
      float4 b = *(const float4*)&xb[(size_t)(2 * i2 + 1) * HW_ + 4 * q];
#pragma unroll
      for (int e = 0; e < 4; ++e) {
        unsigned pk = (unsigned)f2bf(f4e(a, e)) | ((unsigned)f2bf(f4e(b, e)) << 16);
        *(unsigned*)&xT[4 * q + 2 + e][2 * i2] = pk;
      }
    }
    for (int idx = tid; idx < 1792; idx += 256) {
      int row = idx >> 4, cq = idx & 15;
      *(float4*)&buf[row][cq * 8] = *(const float4*)&wp[(size_t)row * 128 + cq * 8];
    }
    // thin assemble: 75 lanes/block x 768 blocks >= 57344 items; hides
    // under the conv phase below (conv doesn't need Gbf).
    if (tid < 75) {
      int L = bid * 75 + tid;
      if (L < N_ * C_ * 32) {
        int n2 = L / 3584;  // 112*32
        int r = L - n2 * 3584;
        int c2 = r >> 5;
        int i0 = 4 * (r & 31);
        const unsigned short* spb = (const unsigned short*)(ws + WS_SPART);
        float s0 = 0.f, s1 = 0.f, s2 = 0.f, s3 = 0.f;
#pragma unroll
        for (int ks2 = 0; ks2 < NKS; ++ks2) {
          ushort4 t =
              *(const ushort4*)&spb[(size_t)(n2 * NKS + ks2) * 14336 + c2 * 128 + i0];
          s0 += bf2f(t.x); s1 += bf2f(t.y); s2 += bf2f(t.z); s3 += bf2f(t.w);
        }
        unsigned short* gbw = (unsigned short*)(ws + WS_GBF);
        if (i0 < 112) {
          const float scale = 1.0f / (48.0f * sqrtf(112.0f));
          const float pc = p19[c2];
          *(ushort4*)&gbw[((size_t)n2 * C_ + c2) * 128 + i0] =
              make_ushort4(f2bf(pc * s0 * scale), f2bf(pc * s1 * scale),
                           f2bf(pc * s2 * scale), f2bf(pc * s3 * scale));
        } else {
          *(ushort4*)&gbw[((size_t)n2 * C_ + c2) * 128 + i0] = make_ushort4(0, 0, 0, 0);
          if (i0 == 112) ws[WS_A + n2 * C_ + c2] = p19[c2] * s0 * (2.0f / 48.0f);
        }
      }
    }
    __syncthreads();
    // conv, kx-outer, accs persistent (R13 structure)
    f32x4 acc[6];
#pragma unroll
    for (int j = 0; j < 6; ++j) acc[j] = (f32x4){0.f, 0.f, 0.f, 0.f};
    unsigned short tv[6][4];
    for (int kx = 0; kx < 3; ++kx) {
      if (kx) {
        __syncthreads();
        for (int idx = tid; idx < 1792; idx += 256) {
          int row = idx >> 4, cq = idx & 15;
          *(float4*)&buf[row][cq * 8] =
              *(const float4*)&wp[(size_t)(kx * 112 + row) * 128 + cq * 8];
        }
        __syncthreads();
      }
#pragma unroll
      for (int j = 0; j < 6; ++j) {
        int t = wv + 4 * j;
        if (t < 21) {
          int m = t / 3, nt = t - 3 * m;
          int o0 = m * 16, w0 = nt * 16;
#pragma unroll
          for (int kb = 0; kb < 4; ++kb) {
            bfrag a = *(const bfrag*)&buf[o0 + lr][8 * lg + 32 * kb];
            bfrag b = *(const bfrag*)&xT[w0 + lr + 2 * kx][8 * lg + 32 * kb];
            acc[j] = __builtin_amdgcn_mfma_f32_16x16x32_bf16(a, b, acc[j], 0, 0, 0);
          }
        }
      }
    }
#pragma unroll
    for (int j = 0; j < 6; ++j) {
      int t = wv + 4 * j;
      if (t < 21) {
        int m = t / 3, nt = t - 3 * m;
        int o0 = m * 16, w0 = nt * 16;
#pragma unroll
        for (int e = 0; e < 4; ++e) {
          float xv = bf2f(xT[w0 + lr + 2][o0 + 4 * lg + e]);
          tv[j][e] = f2bf(fmaxf(-acc[j][e], xv));
        }
      }
    }
    __syncthreads();  // drain conv reads of xT/buf
#pragma unroll
    for (int j = 0; j < 6; ++j) {
      int t = wv + 4 * j;
      if (t < 21) {
        int m = t / 3, nt = t - 3 * m;
        int o0 = m * 16, w0 = nt * 16;
        unsigned pk0 = (unsigned)tv[j][0] | ((unsigned)tv[j][1] << 16);
        unsigned pk1 = (unsigned)tv[j][2] | ((unsigned)tv[j][3] << 16);
        *(unsigned*)&xT[w0 + lr + 2][o0 + 4 * lg] = pk0;
        *(unsigned*)&xT[w0 + lr + 2][o0 + 4 * lg + 2] = pk1;
      }
    }
  }
  grid.sync();  // Gbf/A' complete grid-wide; t13 persists in LDS

  // ============ phase 4: stage Gbf + final GEMM ============
  for (int idx = tid; idx < 1792; idx += 256) {
    int row = idx >> 4, cq = idx & 15;
    *(float4*)&buf[row][cq * 8] = *(const float4*)&gb[(size_t)row * 128 + cq * 8];
  }
  if (tid < 112) sA[tid] = ws[WS_A + n * C_ + tid];
  __syncthreads();
#pragma unroll
  for (int j = 0; j < 6; ++j) {
    int t = wv + 4 * j;
    if (t < 21) {
      int m = t / 3, nt = t - 3 * m;
      int c0 = m * 16, w0 = nt * 16;
      f32x4 acc2 = {0.f, 0.f, 0.f, 0.f};
#pragma unroll
      for (int kb = 0; kb < 4; ++kb) {
        bfrag a = *(const bfrag*)&buf[c0 + lr][8 * lg + 32 * kb];
        bfrag b = *(const bfrag*)&xT[w0 + lr + 2][8 * lg + 32 * kb];
        acc2 = __builtin_amdgcn_mfma_f32_16x16x32_bf16(a, b, acc2, 0, 0, 0);
      }
#pragma unroll
      for (int e = 0; e < 4; ++e) {
        int c = c0 + 4 * lg + e;
        out[((size_t)n * C_ + c) * HW_ + h * W_ + w0 + lr] = sA[c] - acc2[e];
      }
    }
  }
}

// ===========================================================================
// Fallback path: the proven 4-kernel pipeline (R16, 45.5 us).
// ===========================================================================
__global__ __launch_bounds__(192) void ath_t7(const float* __restrict__ x,
                                              const float* __restrict__ p7,
                                              float* __restrict__ ws) {
  const int h = blockIdx.x, n = blockIdx.y;
  const int tid = threadIdx.x;
  __shared__ float q[48];
  __shared__ float wred[3];
  if (tid < 48) {
    float s = 0.f;
#pragma unroll
    for (int k = 0; k < 3; ++k) {
      int wp = tid + 3 - 3 * k;
      if (wp >= 0 && wp < 48) s += p7[k * 48 + wp];
    }
    q[tid] = s;
  }
  __syncthreads();
  const int c16 = tid / 12, qq = tid - 12 * c16;
  const float qv0 = q[4 * qq], qv1 = q[4 * qq + 1];
  const float qv2 = q[4 * qq + 2], qv3 = q[4 * qq + 3];
  float d = 0.f;
#pragma unroll
  for (int p = 0; p < 7; ++p) {
    const int c = c16 + 16 * p;
    float4 v = *(const float4*)&x[((size_t)n * C_ + c) * HW_ + h * W_ + 4 * qq];
    d += v.x * qv0 + v.y * qv1 + v.z * qv2 + v.w * qv3;
  }
#pragma unroll
  for (int off = 32; off >= 1; off >>= 1) d += __shfl_xor(d, off);
  if ((tid & 63) == 0) wred[tid >> 6] = d;
  __syncthreads();
  if (tid == 0)
    ws[WS_T7 + n * H_ + (h + 2) % 48] =
        (wred[0] + wred[1] + wred[2]) * (1.0f / 112.0f);
}

__global__ __launch_bounds__(256) void ath_gram(const float* __restrict__ x,
                                                const float* __restrict__ cw,
                                                float* __restrict__ ws) {
  const int bid = blockIdx.x;
  const int tid = threadIdx.x;
  if (bid >= 2 * NKS * N_) {
    int idx = (bid - 2 * NKS * N_) * 256 + tid;
    if (idx < 3 * 112 * 32) {
      int kx = idx / (112 * 32);
      int r = idx - kx * 112 * 32;
      int o = r >> 5;
      int i0 = (r & 31) * 4;
      unsigned short v[4];
#pragma unroll
      for (int e = 0; e < 4; ++e) {
        int i = i0 + e;
        v[e] = (i < 112) ? f2bf(cw[o * 336 + i * 3 + kx]) : (unsigned short)0;
      }
      unsigned short* wp = (unsigned short*)(ws + WS_WPACK);
      *(ushort4*)&wp[(kx * 112 + o) * 128 + i0] = make_ushort4(v[0], v[1], v[2], v[3]);
    }
    return;
  }
  const int half = bid & 1;
  const int ks = (bid >> 1) % NKS;
  const int n = bid / (2 * NKS);
  const int k0 = ks * 128;
  const int lane = tid & 63, wv = tid >> 6;
  const int lr = lane & 15, lg = lane >> 4;
  __shared__ __align__(16) unsigned short As[112][136];
  __shared__ __align__(16) unsigned short t7r[136];
  __shared__ float t7s[48];
  __shared__ float s17[8];
  if (tid < 48) t7s[tid] = ws[WS_T7 + n * H_ + tid];
  __syncthreads();
  if (tid < 7) {
    float s = 0.f;
    for (int hh = 0; hh < 48; ++hh) {
      int j = 2 * tid + hh - 6;
      if (j >= 0 && j < 48) s += fabsf(t7s[j]);
    }
    s17[tid] = s * (1.0f / 48.0f);
  }
  if (tid >= 64 && tid < 192) t7r[tid - 64] = f2bf(t7s[(k0 + tid - 64) / 48]);
  if (tid >= 192 && tid < 200) t7r[128 + (tid - 192)] = 0;
  const int ti = wv + 4 * half;
  bfrag breg[4];
  if (ti < 7) {
    const float* bp = &x[((size_t)n * C_ + 16 * ti + lr) * HW_ + k0 + 8 * lg];
#pragma unroll
    for (int kb = 0; kb < 4; ++kb) {
      float4 v0 = *(const float4*)(bp + 32 * kb);
      float4 v1 = *(const float4*)(bp + 32 * kb + 4);
      breg[kb][0] = (short)f2bf(v0.x); breg[kb][1] = (short)f2bf(v0.y);
      breg[kb][2] = (short)f2bf(v0.z); breg[kb][3] = (short)f2bf(v0.w);
      breg[kb][4] = (short)f2bf(v1.x); breg[kb][5] = (short)f2bf(v1.y);
      breg[kb][6] = (short)f2bf(v1.z); breg[kb][7] = (short)f2bf(v1.w);
    }
  }
  __syncthreads();
  const int kq = tid & 31, cg2 = tid >> 5;
  const int base7 = (k0 + 4 * kq) % 7;
#pragma unroll
  for (int r = 0; r < 14; ++r) {
    const int c = cg2 + 8 * r;
    float4 v = *(const float4*)&x[((size_t)n * C_ + c) * HW_ + k0 + 4 * kq];
    int cls0 = (base7 + c) % 7;
    unsigned short a4[4];
#pragma unroll
    for (int e = 0; e < 4; ++e) {
      int cl = cls0 + e;
      cl = (cl >= 7) ? cl - 7 : cl;
      a4[e] = f2bf(f4e(v, e) + s17[cl]);
    }
    *(ushort4*)&As[c][4 * kq] = make_ushort4(a4[0], a4[1], a4[2], a4[3]);
  }
  __syncthreads();
  if (ti == 7) {
    const bfrag zero8 = {0, 0, 0, 0, 0, 0, 0, 0};
#pragma unroll
    for (int kb = 0; kb < 4; ++kb)
      breg[kb] = (lr == 0) ? *(const bfrag*)&t7r[8 * lg + 32 * kb] : zero8;
  }
  f32x4 acc[7];
#pragma unroll
  for (int j = 0; j < 7; ++j) acc[j] = (f32x4){0.f, 0.f, 0.f, 0.f};
#pragma unroll
  for (int kb = 0; kb < 4; ++kb) {
#pragma unroll
    for (int tc = 0; tc < 7; ++tc) {
      bfrag a = *(const bfrag*)&As[16 * tc + lr][8 * lg + 32 * kb];
      acc[tc] = __builtin_amdgcn_mfma_f32_16x16x32_bf16(a, breg[kb], acc[tc], 0, 0, 0);
    }
  }
  unsigned short* sp =
      (unsigned short*)(ws + WS_SPART) + (size_t)(n * NKS + ks) * 14336;
#pragma unroll
  for (int tc = 0; tc < 7; ++tc)
#pragma unroll
    for (int e = 0; e < 4; ++e)
      sp[(16 * tc + 4 * lg + e) * 128 + 16 * ti + lr] = f2bf(acc[tc][e]);
}

__global__ __launch_bounds__(128) void ath_assemble(const float* __restrict__ p19,
                                                    float* __restrict__ ws) {
  const int bid = blockIdx.x;
  const int n = bid / 28, g = bid % 28;
  const int tid = threadIdx.x;
  const int cloc = tid >> 5, q = tid & 31;
  const int c = 4 * g + cloc;
  const int i0 = 4 * q;
  const unsigned short* spb = (const unsigned short*)(ws + WS_SPART);
  float s0 = 0.f, s1 = 0.f, s2 = 0.f, s3 = 0.f;
#pragma unroll
  for (int ks = 0; ks < NKS; ++ks) {
    ushort4 t = *(const ushort4*)&spb[(size_t)(n * NKS + ks) * 14336 + c * 128 + i0];
    s0 += bf2f(t.x); s1 += bf2f(t.y); s2 += bf2f(t.z); s3 += bf2f(t.w);
  }
  unsigned short* gb = (unsigned short*)(ws + WS_GBF);
  if (i0 < 112) {
    const float scale = 1.0f / (48.0f * sqrtf(112.0f));
    const float pc = p19[c];
    *(ushort4*)&gb[((size_t)n * C_ + c) * 128 + i0] =
        make_ushort4(f2bf(pc * s0 * scale), f2bf(pc * s1 * scale),
                     f2bf(pc * s2 * scale), f2bf(pc * s3 * scale));
  } else {
    *(ushort4*)&gb[((size_t)n * C_ + c) * 128 + i0] = make_ushort4(0, 0, 0, 0);
    if (i0 == 112) ws[WS_A + n * C_ + c] = p19[c] * s0 * (2.0f / 48.0f);
  }
}

__global__ __launch_bounds__(256) void ath_fused(const float* __restrict__ x,
                                                 const float* __restrict__ ws,
                                                 float* __restrict__ out) {
  const int h = blockIdx.x, n = blockIdx.y;
  const int tid = threadIdx.x;
  const int lane = tid & 63, wv = tid >> 6;
  const int lr = lane & 15, lg = lane >> 4;
  __shared__ __align__(16) unsigned short xT[52][136];
  __shared__ __align__(16) unsigned short buf[112][136];
  __shared__ float sA[112];
  const float* xb = x + (size_t)n * C_ * HW_ + h * W_;
  const unsigned short* wp = (const unsigned short*)(ws + WS_WPACK);
  const unsigned short* gb = (const unsigned short*)(ws + WS_GBF) + (size_t)n * C_ * 128;
  for (int idx = tid; idx < 52 * 24; idx += 256) {
    int r2 = idx / 24, cc = 112 + idx % 24;
    xT[r2][cc] = 0;
  }
  for (int idx = tid; idx < 4 * 112; idx += 256) {
    int rr = idx / 112;
    int r2 = (rr < 2) ? rr : 48 + rr;
    xT[r2][idx % 112] = 0;
  }
  if (tid < 112) sA[tid] = ws[WS_A + n * C_ + tid];
  for (int idx = tid; idx < 672; idx += 256) {
    int i2 = idx / 12, q = idx - i2 * 12;
    float4 a = *(const float4*)&xb[(size_t)(2 * i2) * HW_ + 4 * q];
    float4 b = *(const float4*)&xb[(size_t)(2 * i2 + 1) * HW_ + 4 * q];
#pragma unroll
    for (int e = 0; e < 4; ++e) {
      unsigned pk = (unsigned)f2bf(f4e(a, e)) | ((unsigned)f2bf(f4e(b, e)) << 16);
      *(unsigned*)&xT[4 * q + 2 + e][2 * i2] = pk;
    }
  }
  for (int idx = tid; idx < 1792; idx += 256) {
    int row = idx >> 4, cq = idx & 15;
    *(float4*)&buf[row][cq * 8] = *(const float4*)&wp[(size_t)row * 128 + cq * 8];
  }
  __syncthreads();
  f32x4 acc[6];
#pragma unroll
  for (int j = 0; j < 6; ++j) acc[j] = (f32x4){0.f, 0.f, 0.f, 0.f};
  for (int kx = 0; kx < 3; ++kx) {
    if (kx) {
      __syncthreads();
      for (int idx = tid; idx < 1792; idx += 256) {
        int row = idx >> 4, cq = idx & 15;
        *(float4*)&buf[row][cq * 8] =
            *(const float4*)&wp[(size_t)(kx * 112 + row) * 128 + cq * 8];
      }
      __syncthreads();
    }
#pragma unroll
    for (int j = 0; j < 6; ++j) {
      int t = wv + 4 * j;
      if (t < 21) {
        int m = t / 3, nt = t - 3 * m;
        int o0 = m * 16, w0 = nt * 16;
#pragma unroll
        for (int kb = 0; kb < 4; ++kb) {
          bfrag a = *(const bfrag*)&buf[o0 + lr][8 * lg + 32 * kb];
          bfrag b = *(const bfrag*)&xT[w0 + lr + 2 * kx][8 * lg + 32 * kb];
          acc[j] = __builtin_amdgcn_mfma_f32_16x16x32_bf16(a, b, acc[j], 0, 0, 0);
        }
      }
    }
  }
  unsigned short tv[6][4];
#pragma unroll
  for (int j = 0; j < 6; ++j) {
    int t = wv + 4 * j;
    if (t < 21) {
      int m = t / 3, nt = t - 3 * m;
      int o0 = m * 16, w0 = nt * 16;
#pragma unroll
      for (int e = 0; e < 4; ++e) {
        float xv = bf2f(xT[w0 + lr + 2][o0 + 4 * lg + e]);
        tv[j][e] = f2bf(fmaxf(-acc[j][e], xv));
      }
    }
  }
  __syncthreads();
#pragma unroll
  for (int j = 0; j < 6; ++j) {
    int t = wv + 4 * j;
    if (t < 21) {
      int m = t / 3, nt = t - 3 * m;
      int o0 = m * 16, w0 = nt * 16;
      unsigned pk0 = (unsigned)tv[j][0] | ((unsigned)tv[j][1] << 16);
      unsigned pk1 = (unsigned)tv[j][2] | ((unsigned)tv[j][3] << 16);
      *(unsigned*)&xT[w0 + lr + 2][o0 + 4 * lg] = pk0;
      *(unsigned*)&xT[w0 + lr + 2][o0 + 4 * lg + 2] = pk1;
    }
  }
  for (int idx = tid; idx < 1792; idx += 256) {
    int row = idx >> 4, cq = idx & 15;
    *(float4*)&buf[row][cq * 8] = *(const float4*)&gb[(size_t)row * 128 + cq * 8];
  }
  __syncthreads();
#pragma unroll
  for (int j = 0; j < 6; ++j) {
    int t = wv + 4 * j;
    if (t < 21) {
      int m = t / 3, nt = t - 3 * m;
      int c0 = m * 16, w0 = nt * 16;
      f32x4 acc2 = {0.f, 0.f, 0.f, 0.f};
#pragma unroll
      for (int kb = 0; kb < 4; ++kb) {
        bfrag a = *(const bfrag*)&buf[c0 + lr][8 * lg + 32 * kb];
        bfrag b = *(const bfrag*)&xT[w0 + lr + 2][8 * lg + 32 * kb];
        acc2 = __builtin_amdgcn_mfma_f32_16x16x32_bf16(a, b, acc2, 0, 0, 0);
      }
#pragma unroll
      for (int e = 0; e < 4; ++e) {
        int c = c0 + 4 * lg + e;
        out[((size_t)n * C_ + c) * HW_ + h * W_ + w0 + lr] = sA[c] - acc2[e];
      }
    }
  }
}

// ---------------------------------------------------------------------------
extern "C" void kernel_launch(void* const* d_in, const int* in_sizes, int n_in,
                              void* d_out, int out_size, void* d_ws, size_t ws_size,
                              hipStream_t stream) {
  const float* x = (const float*)d_in[0];
  const float* p7 = (const float*)d_in[1];
  // d_in[2] (p8_w) cancels algebraically: t10 = t8 - (x + t8) = -x
  const float* p19 = (const float*)d_in[3];
  const float* cw = (const float*)d_in[4];
  float* ws = (float*)d_ws;
  float* out = (float*)d_out;

  int maxb = 0;
  hipError_t oe = hipOccupancyMaxActiveBlocksPerMultiprocessor(
      &maxb, (const void*)ath_mega, 256, 0);
  if (oe == hipSuccess && maxb >= 3) {
    void* args[] = {(void*)&x, (void*)&p7, (void*)&p19,
                    (void*)&cw, (void*)&ws, (void*)&out};
    hipLaunchCooperativeKernel((void*)ath_mega, dim3(H_ * N_), dim3(256), args,
                               0, stream);
  } else {
    ath_t7<<<dim3(H_, N_), 192, 0, stream>>>(x, p7, ws);
    ath_gram<<<2 * NKS * N_ + 42, 256, 0, stream>>>(x, cw, ws);
    ath_assemble<<<N_ * 28, 128, 0, stream>>>(p19, ws);
    ath_fused<<<dim3(H_, N_), 256, 0, stream>>>(x, ws, out);
  }
}